// Round 1
// baseline (3572.119 us; speedup 1.0000x reference)
//
#include <hip/hip_runtime.h>
#include <math.h>

#define Bb 256
#define Tt 512
#define Ii 128
#define Hh 256
#define Ss 4
#define G4 1024  // 4*H gate rows

// Weight residency split for k_lstm16r: per thread 64 chunks of 16B (2 rows x 32).
// 48 chunks live in VGPRs (w0[32] + w1[16]), LCH=16 chunks live in LDS.
#define LCH 16
#define SMEM_W_BYTES (LCH * 512 * 16)            // 128 KiB
#define SMEM_BYTES (SMEM_W_BYTES + 512 + 2048)   // + h_h(512B) + f_sh/o_sh(2KB)

typedef _Float16 half2t __attribute__((ext_vector_type(2)));
union W16 { uint4 u; half2t h[4]; };

__device__ __forceinline__ float dot8(uint4 w, uint4 hv, float acc) {
  W16 a; a.u = w; W16 b; b.u = hv;
#if __has_builtin(__builtin_amdgcn_fdot2)
  acc = __builtin_amdgcn_fdot2(a.h[0], b.h[0], acc, false);
  acc = __builtin_amdgcn_fdot2(a.h[1], b.h[1], acc, false);
  acc = __builtin_amdgcn_fdot2(a.h[2], b.h[2], acc, false);
  acc = __builtin_amdgcn_fdot2(a.h[3], b.h[3], acc, false);
#else
#pragma unroll
  for (int k = 0; k < 4; k++)
    acc += (float)a.h[k].x * (float)b.h[k].x + (float)a.h[k].y * (float)b.h[k].y;
#endif
  return acc;
}

// ---------------- kernel 1: lengths[b] = max(sum(mask[b,:]), 1) ----------------
__global__ void k_len(const int* __restrict__ mask, int* __restrict__ len) {
  int b = blockIdx.x, tid = threadIdx.x;
  int c = (mask[b * Tt + tid] != 0) + (mask[b * Tt + 256 + tid] != 0);
#pragma unroll
  for (int off = 32; off > 0; off >>= 1) c += __shfl_down(c, off, 64);
  __shared__ int red[4];
  if ((tid & 63) == 0) red[tid >> 6] = c;
  __syncthreads();
  if (tid == 0) {
    int t = red[0] + red[1] + red[2] + red[3];
    len[b] = t < 1 ? 1 : t;
  }
}

// ---------------- kernel 2: weight transforms --------------------------------
// wt_hh16[(s*32+i8)*1024+o] = 8 halfs {W_hh[s][o][8i8..8i8+7]}
// wt_ih  [(s*32+i4)*1024+o] = float4 {W_ih[s][o][4i4..4i4+3]}   (for k_gx)
// wt_ih16[(s*16+i8)*1024+o] = 8 halfs {W_ih[s][o][8i8..8i8+7]}  (fallback path)
__global__ void k_tr(const float* __restrict__ W_ih, const float* __restrict__ W_hh,
                     uint4* __restrict__ wt_hh16, float4* __restrict__ wt_ih,
                     uint4* __restrict__ wt_ih16) {
  int id = blockIdx.x * blockDim.x + threadIdx.x;
  const int NH16 = Ss * 32 * G4;  // 131072
  const int NI4 = Ss * 32 * G4;   // 131072
  const int NI16 = Ss * 16 * G4;  // 65536
  if (id < NH16) {
    int o = id % G4, i8 = (id / G4) % 32, s = id / (G4 * 32);
    const float* src = W_hh + ((size_t)(s * G4 + o)) * Hh + 8 * i8;
    W16 w;
#pragma unroll
    for (int k = 0; k < 4; k++) {
      w.h[k].x = (_Float16)src[2 * k];
      w.h[k].y = (_Float16)src[2 * k + 1];
    }
    wt_hh16[id] = w.u;
  } else if (id < NH16 + NI4) {
    int id2 = id - NH16;
    int o = id2 % G4, i4 = (id2 / G4) % 32, s = id2 / (G4 * 32);
    wt_ih[id2] = *(const float4*)(W_ih + ((size_t)(s * G4 + o)) * Ii + 4 * i4);
  } else if (id < NH16 + NI4 + NI16) {
    int id3 = id - NH16 - NI4;
    int o = id3 % G4, i8 = (id3 / G4) % 16, s = id3 / (G4 * 16);
    const float* src = W_ih + ((size_t)(s * G4 + o)) * Ii + 8 * i8;
    W16 w;
#pragma unroll
    for (int k = 0; k < 4; k++) {
      w.h[k].x = (_Float16)src[2 * k];
      w.h[k].y = (_Float16)src[2 * k + 1];
    }
    wt_ih16[id3] = w.u;
  }
}

// ---------------- kernel 3: gx[b][t][o] = W_ih[seg]@x + b_ih[seg]+b_hh[seg] ----
__global__ __launch_bounds__(256, 2) void k_gx(
    const float* __restrict__ x, const float4* __restrict__ wt_ih,
    const float* __restrict__ b_ih, const float* __restrict__ b_hh,
    const int* __restrict__ len, float* __restrict__ gx) {
  const int b = blockIdx.x >> 4;
  const int t0 = (blockIdx.x & 15) * 32;
  const int tid = threadIdx.x;
  const int L = len[b];
  if (t0 >= L) return;  // gx never read for t >= L
  __shared__ __align__(16) float xs[32 * Ii];
  __shared__ int segt[32];
  float4* xs4 = (float4*)xs;
  const float4* xsrc = (const float4*)(x + ((size_t)b * Tt + t0) * Ii);
  for (int f = tid; f < 32 * 32; f += 256) xs4[f] = xsrc[f];
  if (tid < 32) {
    int s = (t0 + tid) * Ss / L;
    segt[tid] = s > Ss - 1 ? Ss - 1 : s;
  }
  __syncthreads();
  const int s_lo = segt[0];
  const int s_hi = segt[31];
  for (int s = s_lo; s <= s_hi; s++) {
    float acc[4][32];
#pragma unroll
    for (int g = 0; g < 4; g++)
#pragma unroll
      for (int t = 0; t < 32; t++) acc[g][t] = 0.f;
    const float4* wb = wt_ih + (size_t)s * 32 * G4 + tid;
    for (int i4 = 0; i4 < 32; i4++) {
      float4 w0 = wb[i4 * G4];
      float4 w1 = wb[i4 * G4 + 256];
      float4 w2 = wb[i4 * G4 + 512];
      float4 w3 = wb[i4 * G4 + 768];
#pragma unroll
      for (int t = 0; t < 32; t++) {
        float4 hv = xs4[t * 32 + i4];
        acc[0][t] += w0.x * hv.x + w0.y * hv.y + w0.z * hv.z + w0.w * hv.w;
        acc[1][t] += w1.x * hv.x + w1.y * hv.y + w1.z * hv.z + w1.w * hv.w;
        acc[2][t] += w2.x * hv.x + w2.y * hv.y + w2.z * hv.z + w2.w * hv.w;
        acc[3][t] += w3.x * hv.x + w3.y * hv.y + w3.z * hv.z + w3.w * hv.w;
      }
    }
    float bsum[4];
#pragma unroll
    for (int g = 0; g < 4; g++)
      bsum[g] = b_ih[s * G4 + g * 256 + tid] + b_hh[s * G4 + g * 256 + tid];
#pragma unroll
    for (int t = 0; t < 32; t++) {
      if (segt[t] == s) {
        size_t base = ((size_t)b * Tt + t0 + t) * G4 + tid;
#pragma unroll
        for (int g = 0; g < 4; g++) gx[base + g * 256] = acc[g][t] + bsum[g];
      }
    }
  }
}

// ---------------- kernel 4 (fallback, no-gx): streaming-weight recurrence ------
template <bool USE_GX>
__global__ __launch_bounds__(512, 1) void k_lstm16(
    const float* __restrict__ x, const uint4* __restrict__ wt_hh16,
    const uint4* __restrict__ wt_ih16, const float* __restrict__ b_ih,
    const float* __restrict__ b_hh, const int* __restrict__ len,
    const float* __restrict__ gx, float* __restrict__ out) {
  const int b = blockIdx.x;
  const int tid = threadIdx.x;
  const int u = tid & 255;
  const int pr = tid >> 8;
  const int r0 = u + pr * 256;
  const int r1 = r0 + 512;
  __shared__ __align__(16) _Float16 h_h[Hh];
  __shared__ __align__(16) _Float16 x_h[Ii];
  __shared__ float f_sh[Hh];
  __shared__ float o_sh[Hh];
  if (pr == 0) h_h[u] = (_Float16)0.f;
  float c = 0.f;
  const int L = len[b];
  float* outb = out + (size_t)b * Tt * Hh;
  float* lastb = out + (size_t)Bb * Tt * Hh + (size_t)b * Hh;
  const uint4* h4 = (const uint4*)h_h;
  const uint4* x4 = (const uint4*)x_h;
  for (int t = 0; t < Tt; t++) {
    if (t < L) {  // block-uniform
      int s = t * Ss / L;
      if (s > Ss - 1) s = Ss - 1;
      float a0, a1;
      if (USE_GX) {
        const float* g = gx + ((size_t)b * Tt + t) * G4;
        a0 = g[r0];
        a1 = g[r1];
      } else {
        if (tid < 128) x_h[tid] = (_Float16)x[((size_t)b * Tt + t) * Ii + tid];
        a0 = b_ih[s * G4 + r0] + b_hh[s * G4 + r0];
        a1 = b_ih[s * G4 + r1] + b_hh[s * G4 + r1];
      }
      __syncthreads();  // B1: prev h_h (and x_h) visible
      const uint4* wb = wt_hh16 + (size_t)s * 32 * G4;
#pragma unroll 8
      for (int i8 = 0; i8 < 32; i8++) {
        uint4 hv = h4[i8];  // wave-uniform LDS broadcast
        a0 = dot8(wb[i8 * G4 + r0], hv, a0);
        a1 = dot8(wb[i8 * G4 + r1], hv, a1);
      }
      if (!USE_GX) {
        const uint4* wbi = wt_ih16 + (size_t)s * 16 * G4;
#pragma unroll
        for (int i8 = 0; i8 < 16; i8++) {
          uint4 xv = x4[i8];
          a0 = dot8(wbi[i8 * G4 + r0], xv, a0);
          a1 = dot8(wbi[i8 * G4 + r1], xv, a1);
        }
      }
      if (pr == 1) {
        f_sh[u] = 1.f / (1.f + expf(-a0));
        o_sh[u] = 1.f / (1.f + expf(-a1));
      }
      __syncthreads();  // B2: dot reads done; f/o visible
      if (pr == 0) {
        float ig = 1.f / (1.f + expf(-a0));
        float gg = tanhf(a1);
        c = f_sh[u] * c + ig * gg;
        float h = o_sh[u] * tanhf(c);
        h_h[u] = (_Float16)h;
        outb[(size_t)t * Hh + u] = h;
        if (t == L - 1) lastb[u] = h;
      }
    } else {
      if (pr == 0) outb[(size_t)t * Hh + u] = 0.f;
    }
  }
}

// ---------------- kernel 4r: recurrence with register+LDS-resident W_hh --------
// Thread (u, pr): pr=0 owns rows u (i) and u+512 (g); pr=1 rows u+256 (f), u+768 (o).
// Per thread: row r0 fully in VGPRs (w0[32]); row r1 half in VGPRs (w1[16]),
// half in LDS (lds_w, 128 KiB, thread-private chunks, conflict-free b128 reads).
// Weights reload only at segment transitions (<=4 times per block).
__global__ __launch_bounds__(512, 2) void k_lstm16r(
    const uint4* __restrict__ wt_hh16, const int* __restrict__ len,
    const float* __restrict__ gx, float* __restrict__ out) {
  extern __shared__ uint4 smem_u4[];
  char* smem = (char*)smem_u4;
  uint4* lds_w = (uint4*)smem;                       // LCH*512 uint4 = 128 KiB
  _Float16* h_h = (_Float16*)(smem + SMEM_W_BYTES);  // 512 B
  float* f_sh = (float*)(smem + SMEM_W_BYTES + 512); // 1 KiB
  float* o_sh = f_sh + Hh;                           // 1 KiB
  const int b = blockIdx.x;
  const int tid = threadIdx.x;
  const int u = tid & 255;
  const int pr = tid >> 8;
  const int r0 = u + pr * 256;  // i-row (pr0) or f-row (pr1)
  const int r1 = r0 + 512;      // g-row (pr0) or o-row (pr1); note r1 == tid+512
  if (pr == 0) h_h[u] = (_Float16)0.f;
  float c = 0.f;
  const int L = len[b];
  float* outb = out + (size_t)b * Tt * Hh;
  float* lastb = out + (size_t)Bb * Tt * Hh + (size_t)b * Hh;
  const uint4* h4 = (const uint4*)h_h;
  const float* gxb = gx + (size_t)b * Tt * G4;
  uint4 w0[32];   // 128 VGPRs
  uint4 w1[LCH];  // 64 VGPRs
  int s_cur = -1;
  float ga0 = gxb[r0];  // prefetched gx for next step (includes biases)
  float ga1 = gxb[r1];
  for (int t = 0; t < L; t++) {
    int s = t * Ss / L;
    if (s > Ss - 1) s = Ss - 1;
    if (s != s_cur) {  // block-uniform; happens <= 4 times
      s_cur = s;
      const uint4* wb = wt_hh16 + (size_t)s * 32 * G4;
#pragma unroll
      for (int i8 = 0; i8 < 32; i8++) w0[i8] = wb[i8 * G4 + r0];
#pragma unroll
      for (int i8 = 0; i8 < LCH; i8++) w1[i8] = wb[i8 * G4 + r1];
#pragma unroll
      for (int i8 = LCH; i8 < 32; i8++)
        lds_w[(i8 - LCH) * 512 + tid] = wb[i8 * G4 + r1];  // own chunks only
    }
    float a0 = ga0, a1 = ga1;
    float a0b = 0.f, a1b = 0.f;  // second chain: halves dependent-chain depth
    if (t + 1 < L) {
      ga0 = gxb[(size_t)(t + 1) * G4 + r0];
      ga1 = gxb[(size_t)(t + 1) * G4 + r1];
    }
    __syncthreads();  // B1: h_h from prev step visible
#pragma unroll
    for (int i8 = 0; i8 < LCH; i8++) {
      uint4 hv = h4[i8];  // wave-uniform LDS broadcast
      if (i8 & 1) { a0b = dot8(w0[i8], hv, a0b); a1b = dot8(w1[i8], hv, a1b); }
      else        { a0  = dot8(w0[i8], hv, a0 ); a1  = dot8(w1[i8], hv, a1 ); }
    }
#pragma unroll
    for (int i8 = LCH; i8 < 32; i8++) {
      uint4 hv = h4[i8];
      uint4 wl = lds_w[(i8 - LCH) * 512 + tid];  // contiguous b128, conflict-free
      if (i8 & 1) { a0b = dot8(w0[i8], hv, a0b); a1b = dot8(wl, hv, a1b); }
      else        { a0  = dot8(w0[i8], hv, a0 ); a1  = dot8(wl, hv, a1 ); }
    }
    a0 += a0b;
    a1 += a1b;
    if (pr == 1) {
      f_sh[u] = 1.f / (1.f + expf(-a0));
      o_sh[u] = 1.f / (1.f + expf(-a1));
    }
    __syncthreads();  // B2: dot reads of h done; f/o visible
    if (pr == 0) {
      float ig = 1.f / (1.f + expf(-a0));
      float gg = tanhf(a1);
      c = f_sh[u] * c + ig * gg;
      float h = o_sh[u] * tanhf(c);
      h_h[u] = (_Float16)h;
      outb[(size_t)t * Hh + u] = h;
      if (t == L - 1) lastb[u] = h;
    }
  }
  // zero tail outside the barriered loop (block-uniform L, no divergence)
  if (pr == 0) {
    for (int t = L; t < Tt; t++) outb[(size_t)t * Hh + u] = 0.f;
  }
}

extern "C" void kernel_launch(void* const* d_in, const int* in_sizes, int n_in,
                              void* d_out, int out_size, void* d_ws, size_t ws_size,
                              hipStream_t stream) {
  const float* x = (const float*)d_in[0];
  const int* mask = (const int*)d_in[1];
  const float* W_ih = (const float*)d_in[2];
  const float* W_hh = (const float*)d_in[3];
  const float* b_ih = (const float*)d_in[4];
  const float* b_hh = (const float*)d_in[5];
  float* out = (float*)d_out;
  char* ws = (char*)d_ws;

  const size_t HH16_OFF = 0;
  const size_t HH16_BYTES = (size_t)Ss * 32 * G4 * 16;  // 2 MiB
  const size_t IH4_OFF = HH16_OFF + HH16_BYTES;
  const size_t IH4_BYTES = (size_t)Ss * 32 * G4 * 16;   // 2 MiB
  const size_t IH16_OFF = IH4_OFF + IH4_BYTES;
  const size_t IH16_BYTES = (size_t)Ss * 16 * G4 * 16;  // 1 MiB
  const size_t LEN_OFF = IH16_OFF + IH16_BYTES;
  const size_t LEN_BYTES = 65536;
  const size_t GX_OFF = LEN_OFF + LEN_BYTES;
  const size_t GX_BYTES = (size_t)Bb * Tt * G4 * 4;     // 512 MiB

  uint4* wt_hh16 = (uint4*)(ws + HH16_OFF);
  float4* wt_ih = (float4*)(ws + IH4_OFF);
  uint4* wt_ih16 = (uint4*)(ws + IH16_OFF);
  int* len = (int*)(ws + LEN_OFF);
  float* gx = (float*)(ws + GX_OFF);
  bool use_gx = ws_size >= GX_OFF + GX_BYTES;

  k_len<<<Bb, 256, 0, stream>>>(mask, len);
  k_tr<<<1280, 256, 0, stream>>>(W_ih, W_hh, wt_hh16, wt_ih, wt_ih16);
  if (use_gx) {
    static bool attr_done = false;
    if (!attr_done) {
      (void)hipFuncSetAttribute((const void*)k_lstm16r,
                                hipFuncAttributeMaxDynamicSharedMemorySize,
                                SMEM_BYTES);
      attr_done = true;
    }
    k_gx<<<Bb * 16, 256, 0, stream>>>(x, wt_ih, b_ih, b_hh, len, gx);
    k_lstm16r<<<Bb, 512, SMEM_BYTES, stream>>>(wt_hh16, len, gx, out);
  } else {
    k_lstm16<false><<<Bb, 512, 0, stream>>>(x, wt_hh16, wt_ih16, b_ih, b_hh, len,
                                            (const float*)nullptr, out);
  }
}

// Round 3
// 2521.907 us; speedup vs baseline: 1.4164x; 1.4164x over previous
//
#include <hip/hip_runtime.h>
#include <math.h>

#define Bb 256
#define Tt 512
#define Ii 128
#define Hh 256
#define Ss 4
#define G4 1024  // 4*H gate rows

// Residency split for k_fused (per thread, 2 gate rows, 32 hh-chunks each):
//   row r0: wh0[32] in VGPRs (128 regs)
//   row r1: chunks 0..LCH-1 in LDS, LCH..LCH+VR1-1 in VGPRs, last 3 streamed (L1)
#define LCH 18   // LDS-resident r1 chunks -> 144 KiB
#define VR1 11   // VGPR-resident r1 chunks (44 regs); streamed = 32-LCH-VR1 = 3
#define TILE 8   // x-gate precompute tile (xg in 16 fp32 regs)

typedef _Float16 half2t __attribute__((ext_vector_type(2)));
union W16 { uint4 u; half2t h[4]; };
union CV8 { _Float16 h[4]; uint2 u; };

__device__ __forceinline__ float dot8(uint4 w, uint4 hv, float acc) {
  W16 a; a.u = w; W16 b; b.u = hv;
#if __has_builtin(__builtin_amdgcn_fdot2)
  acc = __builtin_amdgcn_fdot2(a.h[0], b.h[0], acc, false);
  acc = __builtin_amdgcn_fdot2(a.h[1], b.h[1], acc, false);
  acc = __builtin_amdgcn_fdot2(a.h[2], b.h[2], acc, false);
  acc = __builtin_amdgcn_fdot2(a.h[3], b.h[3], acc, false);
#else
#pragma unroll
  for (int k = 0; k < 4; k++)
    acc += (float)a.h[k].x * (float)b.h[k].x + (float)a.h[k].y * (float)b.h[k].y;
#endif
  return acc;
}

// ---------------- kernel 1: lengths[b] = max(sum(mask[b,:]), 1) ----------------
__global__ void k_len(const int* __restrict__ mask, int* __restrict__ len) {
  int b = blockIdx.x, tid = threadIdx.x;
  int c = (mask[b * Tt + tid] != 0) + (mask[b * Tt + 256 + tid] != 0);
#pragma unroll
  for (int off = 32; off > 0; off >>= 1) c += __shfl_down(c, off, 64);
  __shared__ int red[4];
  if ((tid & 63) == 0) red[tid >> 6] = c;
  __syncthreads();
  if (tid == 0) {
    int t = red[0] + red[1] + red[2] + red[3];
    len[b] = t < 1 ? 1 : t;
  }
}

// ---------------- kernel 2: weight transforms (fp32 -> packed fp16) ------------
// wt_hh16[(s*32+i8)*1024+o] = 8 halfs {W_hh[s][o][8i8..8i8+7]}
// wt_ih16[(s*16+i8)*1024+o] = 8 halfs {W_ih[s][o][8i8..8i8+7]}
__global__ void k_tr(const float* __restrict__ W_ih, const float* __restrict__ W_hh,
                     uint4* __restrict__ wt_hh16, uint4* __restrict__ wt_ih16) {
  int id = blockIdx.x * blockDim.x + threadIdx.x;
  const int NH16 = Ss * 32 * G4;  // 131072
  const int NI16 = Ss * 16 * G4;  // 65536
  if (id < NH16) {
    int o = id % G4, i8 = (id / G4) % 32, s = id / (G4 * 32);
    const float* src = W_hh + ((size_t)(s * G4 + o)) * Hh + 8 * i8;
    W16 w;
#pragma unroll
    for (int k = 0; k < 4; k++) {
      w.h[k].x = (_Float16)src[2 * k];
      w.h[k].y = (_Float16)src[2 * k + 1];
    }
    wt_hh16[id] = w.u;
  } else if (id < NH16 + NI16) {
    int id3 = id - NH16;
    int o = id3 % G4, i8 = (id3 / G4) % 16, s = id3 / (G4 * 16);
    const float* src = W_ih + ((size_t)(s * G4 + o)) * Ii + 8 * i8;
    W16 w;
#pragma unroll
    for (int k = 0; k < 4; k++) {
      w.h[k].x = (_Float16)src[2 * k];
      w.h[k].y = (_Float16)src[2 * k + 1];
    }
    wt_ih16[id3] = w.u;
  }
}

// ---------------- kernel 3: fused recurrence, weight-resident ------------------
// 512 threads = 8 waves, 1 block/CU (LDS-capped). Thread (u=tid&255, pr=tid>>8)
// owns rows r0 = u+pr*256 (i or f) and r1 = r0+512 (g or o). pr=1 sends
// sigmoid(f), sigmoid(o) via LDS; pr=0 keeps c and writes h.
// Per TILE steps: stage x->fp16 LDS, compute xg[2][TILE] (W_ih@x + bias) with
// W_ih streamed once per tile. Per step: 64 hh-dot8 from resident chunks;
// W_hh (re)loads only at <=4 block-uniform segment transitions.
__global__ __launch_bounds__(512, 2) void k_fused(
    const float* __restrict__ x, const uint4* __restrict__ wt_hh16,
    const uint4* __restrict__ wt_ih16, const float* __restrict__ b_ih,
    const float* __restrict__ b_hh, const int* __restrict__ len,
    float* __restrict__ out) {
  __shared__ __align__(16) uint4 lds_w[LCH * 512];   // 144 KiB, thread-private chunks
  __shared__ __align__(16) _Float16 xs[TILE * Ii];   // 2 KiB x tile (fp16)
  __shared__ __align__(16) _Float16 h_h[Hh];         // 512 B
  __shared__ float f_sh[Hh];
  __shared__ float o_sh[Hh];
  const int b = blockIdx.x;
  const int tid = threadIdx.x;
  const int u = tid & 255;
  const int pr = tid >> 8;
  const int r0 = u + pr * 256;
  const int r1 = r0 + 512;
  const int L = len[b];
  // segment boundaries: seg(t) = #{tb_i <= t}, tb_i = ceil(i*L/4)
  const int tb1 = (L + 3) >> 2;
  const int tb2 = (2 * L + 3) >> 2;
  const int tb3 = (3 * L + 3) >> 2;
  if (pr == 0) h_h[u] = (_Float16)0.f;
  float c = 0.f;
  float* outb = out + (size_t)b * Tt * Hh;
  float* lastb = out + (size_t)Bb * Tt * Hh + (size_t)b * Hh;
  const uint4* h4 = (const uint4*)h_h;
  const uint4* xs4 = (const uint4*)xs;
  uint4 wh0[32];   // r0 hh chunks, 128 VGPRs
  uint4 wr1[VR1];  // r1 hh chunks LCH..LCH+VR1-1, 44 VGPRs
  int s_cur = -1;
  float xg0[TILE], xg1[TILE];

  for (int t0 = 0; t0 < L; t0 += TILE) {  // t0 multiple of 8, t0 <= 504: no x overrun
    // ---- stage x[b, t0..t0+TILE) -> fp16 LDS ----
    if (tid < TILE * Ii / 4) {  // 256 threads, one float4 each
      float4 xf = ((const float4*)(x + ((size_t)b * Tt + t0) * Ii))[tid];
      CV8 cv;
      cv.h[0] = (_Float16)xf.x;
      cv.h[1] = (_Float16)xf.y;
      cv.h[2] = (_Float16)xf.z;
      cv.h[3] = (_Float16)xf.w;
      ((uint2*)xs)[tid] = cv.u;
    }
    __syncthreads();  // xs visible (also h_h init before first step)

    // ---- per-tile segment ids (block-uniform) ----
    int segv[TILE];
#pragma unroll
    for (int tt = 0; tt < TILE; tt++) {
      int t = t0 + tt;
      segv[tt] = (t >= tb1) + (t >= tb2) + (t >= tb3);
    }
    const int s_lo = segv[0];
    const int tlast = (t0 + TILE - 1 < L) ? (t0 + TILE - 1) : (L - 1);
    const int s_hi = (tlast >= tb1) + (tlast >= tb2) + (tlast >= tb3);

    // ---- phase A (merged rows): xg[row][tt] = W_ih[seg(t)]@x_t + bias ----------
    for (int s = s_lo; s <= s_hi; s++) {  // <= 2 iterations
      float acc0[TILE], acc1[TILE];
#pragma unroll
      for (int tt = 0; tt < TILE; tt++) { acc0[tt] = 0.f; acc1[tt] = 0.f; }
      const uint4* wbi = wt_ih16 + ((size_t)s * 16) * G4;
#pragma unroll 2
      for (int i8 = 0; i8 < 16; i8++) {  // W_ih streamed once per tile, reused 8x
        uint4 w0 = wbi[(size_t)i8 * G4 + r0];
        uint4 w1 = wbi[(size_t)i8 * G4 + r1];
#pragma unroll
        for (int tt = 0; tt < TILE; tt++) {
          uint4 hv = xs4[tt * 16 + i8];  // wave-uniform LDS broadcast, shared rows
          acc0[tt] = dot8(w0, hv, acc0[tt]);
          acc1[tt] = dot8(w1, hv, acc1[tt]);
        }
      }
      float bias0 = b_ih[s * G4 + r0] + b_hh[s * G4 + r0];
      float bias1 = b_ih[s * G4 + r1] + b_hh[s * G4 + r1];
#pragma unroll
      for (int tt = 0; tt < TILE; tt++) {
        if (segv[tt] == s) {
          xg0[tt] = acc0[tt] + bias0;
          xg1[tt] = acc1[tt] + bias1;
        }
      }
    }

    // ---- recurrence steps (fully unrolled: xg/wh0/wr1 statically indexed) ----
#pragma unroll
    for (int tt = 0; tt < TILE; tt++) {
      const int t = t0 + tt;
      if (t < L) {  // block-uniform
        const int s = segv[tt];
        if (s != s_cur) {  // block-uniform, <= 4 times total
          s_cur = s;
          const uint4* wb = wt_hh16 + (size_t)s * 32 * G4;
#pragma unroll
          for (int i8 = 0; i8 < 32; i8++) wh0[i8] = wb[(size_t)i8 * G4 + r0];
#pragma unroll
          for (int i8 = 0; i8 < LCH; i8++)
            lds_w[i8 * 512 + tid] = wb[(size_t)i8 * G4 + r1];  // own chunks only
#pragma unroll
          for (int k = 0; k < VR1; k++)
            wr1[k] = wb[(size_t)(LCH + k) * G4 + r1];
        }
        // streamed r1 chunks (same address each step; 24KB/CU -> L1-resident)
        const uint4* wbs = wt_hh16 + ((size_t)s_cur * 32) * G4 + r1;
        uint4 st0 = wbs[(size_t)(LCH + VR1 + 0) * G4];
        uint4 st1 = wbs[(size_t)(LCH + VR1 + 1) * G4];
        uint4 st2 = wbs[(size_t)(LCH + VR1 + 2) * G4];
        float a0 = xg0[tt], a1 = xg1[tt];
        float a0b = 0.f, a1b = 0.f;  // even/odd chains halve dependency depth
        __syncthreads();  // B1: prev h_h visible
#pragma unroll
        for (int i8 = 0; i8 < LCH; i8++) {
          uint4 hv = h4[i8];                 // wave-uniform broadcast
          uint4 wl = lds_w[i8 * 512 + tid];  // contiguous b128, conflict-free
          if (i8 & 1) { a0b = dot8(wh0[i8], hv, a0b); a1b = dot8(wl, hv, a1b); }
          else        { a0  = dot8(wh0[i8], hv, a0 ); a1  = dot8(wl, hv, a1 ); }
        }
#pragma unroll
        for (int i8 = LCH; i8 < LCH + VR1; i8++) {
          uint4 hv = h4[i8];
          if (i8 & 1) { a0b = dot8(wh0[i8], hv, a0b); a1b = dot8(wr1[i8 - LCH], hv, a1b); }
          else        { a0  = dot8(wh0[i8], hv, a0 ); a1  = dot8(wr1[i8 - LCH], hv, a1 ); }
        }
        {
          uint4 hv;
          hv = h4[LCH + VR1 + 0];
          a0  = dot8(wh0[LCH + VR1 + 0], hv, a0 );
          a1  = dot8(st0, hv, a1);
          hv = h4[LCH + VR1 + 1];
          a0b = dot8(wh0[LCH + VR1 + 1], hv, a0b);
          a1b = dot8(st1, hv, a1b);
          hv = h4[LCH + VR1 + 2];
          a0  = dot8(wh0[LCH + VR1 + 2], hv, a0 );
          a1  = dot8(st2, hv, a1);
        }
        a0 += a0b;
        a1 += a1b;
        if (pr == 1) {
          f_sh[u] = 1.f / (1.f + expf(-a0));
          o_sh[u] = 1.f / (1.f + expf(-a1));
        }
        __syncthreads();  // B2: h reads done; f/o visible
        if (pr == 0) {
          float ig = 1.f / (1.f + expf(-a0));
          float gg = tanhf(a1);
          c = f_sh[u] * c + ig * gg;
          float h = o_sh[u] * tanhf(c);
          h_h[u] = (_Float16)h;
          outb[(size_t)t * Hh + u] = h;
          if (t == L - 1) lastb[u] = h;
        }
      }
    }
  }
  // zero tail t >= L (all 512 threads, coalesced float4)
  {
    const int ztotal = (Tt - L) * (Hh / 4);
    float4* zb = (float4*)(outb + (size_t)L * Hh);
    float4 z; z.x = z.y = z.z = z.w = 0.f;
    for (int i = tid; i < ztotal; i += 512) zb[i] = z;
  }
}

extern "C" void kernel_launch(void* const* d_in, const int* in_sizes, int n_in,
                              void* d_out, int out_size, void* d_ws, size_t ws_size,
                              hipStream_t stream) {
  const float* x = (const float*)d_in[0];
  const int* mask = (const int*)d_in[1];
  const float* W_ih = (const float*)d_in[2];
  const float* W_hh = (const float*)d_in[3];
  const float* b_ih = (const float*)d_in[4];
  const float* b_hh = (const float*)d_in[5];
  float* out = (float*)d_out;
  char* ws = (char*)d_ws;

  const size_t HH16_OFF = 0;
  const size_t HH16_BYTES = (size_t)Ss * 32 * G4 * 16;  // 2 MiB
  const size_t IH16_OFF = HH16_OFF + HH16_BYTES;
  const size_t IH16_BYTES = (size_t)Ss * 16 * G4 * 16;  // 1 MiB
  const size_t LEN_OFF = IH16_OFF + IH16_BYTES;

  uint4* wt_hh16 = (uint4*)(ws + HH16_OFF);
  uint4* wt_ih16 = (uint4*)(ws + IH16_OFF);
  int* len = (int*)(ws + LEN_OFF);

  k_len<<<Bb, 256, 0, stream>>>(mask, len);
  k_tr<<<768, 256, 0, stream>>>(W_ih, W_hh, wt_hh16, wt_ih16);
  k_fused<<<Bb, 512, 0, stream>>>(x, wt_hh16, wt_ih16, b_ih, b_hh, len, out);
}